// Round 10
// baseline (635.444 us; speedup 1.0000x reference)
//
#include <hip/hip_runtime.h>

#define N_SERVICES 50000
#define N_PAD      50048   // 782*64
#define N_EDGES    1600000
#define N_CTX      6144    // BATCH*CONTEXT
#define EMB        32
#define BATCH      2048
#define FIN        128     // (CONTEXT+1)*EMB
#define N_TILES    782
#define BM         128
#define M_CHUNKS   16      // 2048 / BM
#define N_CHAINS   64
#define GEMM_BLKS  (M_CHUNKS * N_CHAINS)   // 1024
#define RUN_BASE   12      // 782 = 64*12 + 14 -> first 14 chains take 13 tiles
#define RUN_EXTRA  14
#define GEMM_REP   4       // DIAGNOSTIC: repeat tile sweep (idempotent) to surface counters
#define CE_BLKS    ((N_EDGES / 4 + 255) / 256)

typedef __attribute__((ext_vector_type(4))) float f32x4;
typedef __attribute__((ext_vector_type(2))) float f32x2;
typedef __attribute__((ext_vector_type(8))) short short8;

__device__ inline unsigned short f2bf(float f) {
    unsigned u = __float_as_uint(f);
    unsigned r = (u + 0x7FFFu + ((u >> 16) & 1u)) >> 16;
    return (unsigned short)r;
}
__device__ inline float bf2f(unsigned short b) {
    return __uint_as_float(((unsigned)b) << 16);
}

// ---------------- degree count (int4: 4 edges/thread) ----------------

__global__ void k_count_degi(const int* __restrict__ dst, int* __restrict__ degi) {
    int e4 = (blockIdx.x * 256 + threadIdx.x) * 4;
    if (e4 < N_EDGES) {            // N_EDGES%4==0: all-or-nothing
        int4 d = *(const int4*)(dst + e4);
        atomicAdd(&degi[d.x], 1);
        atomicAdd(&degi[d.y], 1);
        atomicAdd(&degi[d.z], 1);
        atomicAdd(&degi[d.w], 1);
    }
}

// ---------------- prefix scan (2 kernels); dis folded in ----------------

__global__ void k_scan_block(const int* __restrict__ degi, float* __restrict__ dis,
                             int* __restrict__ tmp, int* __restrict__ blocksum) {
    __shared__ int s[256];
    int t = threadIdx.x, i = blockIdx.x * 256 + t;
    int v = (i < N_SERVICES) ? degi[i] : 0;
    if (i < N_SERVICES) dis[i] = rsqrtf((float)(v + 1));  // +1 self-loop
    s[t] = v;
    __syncthreads();
#pragma unroll
    for (int o = 1; o < 256; o <<= 1) {
        int x = 0;
        if (t >= o) x = s[t - o];
        __syncthreads();
        if (t >= o) s[t] += x;
        __syncthreads();
    }
    if (i < N_SERVICES) tmp[i] = s[t] - v;       // exclusive within block
    if (t == 255) blocksum[blockIdx.x] = s[255];
}

// merged: scan the 196 block sums redundantly per block, finish row_start/cursor,
// and mark the context-node mask (mask zeroed earlier in k_cvtW)
__global__ void k_scan_fin(const int* __restrict__ tmp, const int* __restrict__ blocksum,
                           int* __restrict__ row_start, int* __restrict__ cursor,
                           const int* __restrict__ ctx_idx, int* __restrict__ mask) {
    __shared__ int s[256];
    int t = threadIdx.x;
    int v = (t < 196) ? blocksum[t] : 0;
    s[t] = v;
    __syncthreads();
#pragma unroll
    for (int o = 1; o < 256; o <<= 1) {
        int x = 0;
        if (t >= o) x = s[t - o];
        __syncthreads();
        if (t >= o) s[t] += x;
        __syncthreads();
    }
    int prefix = (blockIdx.x == 0) ? 0 : s[blockIdx.x - 1];  // exclusive block prefix
    int i = blockIdx.x * 256 + t;
    if (i < N_SERVICES) {
        int r = tmp[i] + prefix;
        row_start[i] = r;
        cursor[i] = r;
    }
    if (i < N_CTX) mask[ctx_idx[i]] = 1;
    if (i == 0) row_start[N_SERVICES] = N_EDGES;
}

// ---------------- CSR fill (int4: 4 edges/thread) ----------------

__global__ void k_fill(const int* __restrict__ src, const int* __restrict__ dst,
                       int* __restrict__ cursor, int* __restrict__ csr_src) {
    int e4 = (blockIdx.x * 256 + threadIdx.x) * 4;
    if (e4 < N_EDGES) {
        int4 s = *(const int4*)(src + e4);
        int4 d = *(const int4*)(dst + e4);
        csr_src[atomicAdd(&cursor[d.x], 1)] = s.x;
        csr_src[atomicAdd(&cursor[d.y], 1)] = s.y;
        csr_src[atomicAdd(&cursor[d.z], 1)] = s.z;
        csr_src[atomicAdd(&cursor[d.w], 1)] = s.w;
    }
}

// ---------------- GCN pieces ----------------

// h' (bf16) = (in @ W) * dis[node]   — dis pre-multiplied so agg is a plain sum
__global__ void k_transform(const float* __restrict__ in, const float* __restrict__ W,
                            const float* __restrict__ dis, unsigned short* __restrict__ h) {
    __shared__ float Ws[EMB][EMB + 1];
    __shared__ float rows[8][EMB];
    int t = threadIdx.x;
    int j = t & 31, li = t >> 5;
    for (int i = t; i < EMB * EMB; i += 256) Ws[i >> 5][i & 31] = W[i];
    int node = blockIdx.x * 8 + li;
    if (node < N_SERVICES) rows[li][j] = in[node * EMB + j];
    __syncthreads();
    if (node < N_SERVICES) {
        float acc = 0.f;
#pragma unroll
        for (int k = 0; k < EMB; ++k) acc = fmaf(rows[li][k], Ws[k][j], acc);
        h[node * EMB + j] = f2bf(acc * dis[node]);
    }
}

// Fused layer-1 agg + ReLU + layer-2 transform:
//   g1[n][:] = relu(dis[n]*(Σ_{s∈N(n)} h1'[s] + h1'[n]) + b1)   (kept in LDS only)
//   h2'[n][:] = (g1[n][:] @ W2) * dis[n]                        (bf16 out)
// 16 nodes per block (3125*16 = 50000 exact), 16 lanes per node in phase 1.
__global__ __launch_bounds__(256) void k_agg_tf(
    const int* __restrict__ row_start, const int* __restrict__ csr_src,
    const float* __restrict__ dis, const unsigned int* __restrict__ h2,
    const float* __restrict__ b, const float* __restrict__ W2,
    unsigned short* __restrict__ hout) {
    __shared__ float gr[16][33];
    __shared__ float Ws[32][33];
    int t = threadIdx.x;
    for (int i = t; i < EMB * EMB; i += 256) Ws[i >> 5][i & 31] = W2[i];

    int j2 = t & 15;                       // dim pair
    int local = t >> 4;
    int node = blockIdx.x * 16 + local;
    int e = row_start[node], e1 = row_start[node + 1];
    float al0 = 0.f, ah0 = 0.f, al1 = 0.f, ah1 = 0.f;
    float al2 = 0.f, ah2 = 0.f, al3 = 0.f, ah3 = 0.f;
    for (; e + 4 <= e1; e += 4) {
        int s0 = csr_src[e], s1 = csr_src[e + 1], s2 = csr_src[e + 2], s3 = csr_src[e + 3];
        unsigned v0 = h2[s0 * 16 + j2], v1 = h2[s1 * 16 + j2];
        unsigned v2 = h2[s2 * 16 + j2], v3 = h2[s3 * 16 + j2];
        al0 += bf2f((unsigned short)(v0 & 0xffff)); ah0 += bf2f((unsigned short)(v0 >> 16));
        al1 += bf2f((unsigned short)(v1 & 0xffff)); ah1 += bf2f((unsigned short)(v1 >> 16));
        al2 += bf2f((unsigned short)(v2 & 0xffff)); ah2 += bf2f((unsigned short)(v2 >> 16));
        al3 += bf2f((unsigned short)(v3 & 0xffff)); ah3 += bf2f((unsigned short)(v3 >> 16));
    }
    for (; e < e1; ++e) {
        unsigned v0 = h2[csr_src[e] * 16 + j2];
        al0 += bf2f((unsigned short)(v0 & 0xffff)); ah0 += bf2f((unsigned short)(v0 >> 16));
    }
    float dn = dis[node];
    unsigned vn = h2[node * 16 + j2];
    float lo = dn * ((al0 + al1) + (al2 + al3) + bf2f((unsigned short)(vn & 0xffff))) + b[j2 * 2];
    float hi = dn * ((ah0 + ah1) + (ah2 + ah3) + bf2f((unsigned short)(vn >> 16))) + b[j2 * 2 + 1];
    gr[local][j2 * 2]     = fmaxf(lo, 0.f);
    gr[local][j2 * 2 + 1] = fmaxf(hi, 0.f);
    __syncthreads();

    // phase 2: transform the block's 16 g1 rows by W2; 2 nodes per thread
    int d = t & 31;
    int l0 = t >> 5;                       // 0..7
    float s0 = 0.f, s1 = 0.f;
#pragma unroll
    for (int k = 0; k < EMB; ++k) {
        float w = Ws[k][d];
        s0 = fmaf(gr[l0][k], w, s0);
        s1 = fmaf(gr[l0 + 8][k], w, s1);
    }
    int n0 = blockIdx.x * 16 + l0;
    hout[(size_t)n0 * EMB + d]       = f2bf(s0 * dis[n0]);
    hout[(size_t)(n0 + 8) * EMB + d] = f2bf(s1 * dis[n0 + 8]);
}

// layer-2 aggregation, masked to context nodes
template <bool RELU, bool MASKED>
__global__ void k_agg(const int* __restrict__ row_start, const int* __restrict__ csr_src,
                      const float* __restrict__ dis, const unsigned int* __restrict__ h2,
                      const float* __restrict__ b, const int* __restrict__ mask,
                      float* __restrict__ out) {
    int t = threadIdx.x;
    int j2 = t & 15;                       // dim pair
    int node = blockIdx.x * 16 + (t >> 4);
    if (node >= N_SERVICES) return;
    if (MASKED && !mask[node]) return;
    int e = row_start[node], e1 = row_start[node + 1];
    float al0 = 0.f, ah0 = 0.f, al1 = 0.f, ah1 = 0.f;
    float al2 = 0.f, ah2 = 0.f, al3 = 0.f, ah3 = 0.f;
    for (; e + 4 <= e1; e += 4) {
        int s0 = csr_src[e], s1 = csr_src[e + 1], s2 = csr_src[e + 2], s3 = csr_src[e + 3];
        unsigned v0 = h2[s0 * 16 + j2], v1 = h2[s1 * 16 + j2];
        unsigned v2 = h2[s2 * 16 + j2], v3 = h2[s3 * 16 + j2];
        al0 += bf2f((unsigned short)(v0 & 0xffff)); ah0 += bf2f((unsigned short)(v0 >> 16));
        al1 += bf2f((unsigned short)(v1 & 0xffff)); ah1 += bf2f((unsigned short)(v1 >> 16));
        al2 += bf2f((unsigned short)(v2 & 0xffff)); ah2 += bf2f((unsigned short)(v2 >> 16));
        al3 += bf2f((unsigned short)(v3 & 0xffff)); ah3 += bf2f((unsigned short)(v3 >> 16));
    }
    for (; e < e1; ++e) {
        unsigned v0 = h2[csr_src[e] * 16 + j2];
        al0 += bf2f((unsigned short)(v0 & 0xffff)); ah0 += bf2f((unsigned short)(v0 >> 16));
    }
    float dn = dis[node];
    unsigned vn = h2[node * 16 + j2];
    float lo = dn * ((al0 + al1) + (al2 + al3) + bf2f((unsigned short)(vn & 0xffff))) + b[j2 * 2];
    float hi = dn * ((ah0 + ah1) + (ah2 + ah3) + bf2f((unsigned short)(vn >> 16))) + b[j2 * 2 + 1];
    if (RELU) { lo = fmaxf(lo, 0.f); hi = fmaxf(hi, 0.f); }
    f32x2 o; o.x = lo; o.y = hi;
    *(f32x2*)&out[node * EMB + j2 * 2] = o;
}

// ---------------- feature gather (emit bf16) ----------------

__global__ void k_gather(const int* __restrict__ user_idx, const int* __restrict__ ctx_idx,
                         const float* __restrict__ user_emb, const float* __restrict__ g2,
                         unsigned short* __restrict__ x) {
    int t = blockIdx.x * 256 + threadIdx.x;  // grid exact: BATCH*FIN
    int b = t >> 7, p = t & 127;
    float v;
    if (p < EMB) {
        v = user_emb[user_idx[b] * EMB + p];
    } else {
        int c = (p - EMB) >> 5, j = p & 31;
        v = g2[ctx_idx[b * 3 + c] * EMB + j];
    }
    x[t] = f2bf(v);
}

// ---------------- fc_W transpose+convert + zero degi/mask ----------------

__global__ __launch_bounds__(256) void k_cvtW(const float* __restrict__ W,
                                              short* __restrict__ Wt,
                                              int* __restrict__ degi,
                                              int* __restrict__ mask) {
    int gid = blockIdx.x * 256 + threadIdx.x;
    if (gid < N_SERVICES) { degi[gid] = 0; mask[gid] = 0; }

    __shared__ short lds[128][33];
    int t = threadIdx.x;
    int n0 = blockIdx.x * 32;
    int nx = t & 31;
    int n  = n0 + nx;
    int kg = t >> 5;                 // 0..7
#pragma unroll
    for (int r = 0; r < 16; ++r) {
        int k = r * 8 + kg;
        float v = (n < N_SERVICES) ? W[k * N_SERVICES + n] : 0.f;
        lds[k][nx] = (short)f2bf(v);
    }
    __syncthreads();
    int nr = t >> 3;                 // 0..31
    int kc = (t & 7) * 16;
    short tmp[16];
#pragma unroll
    for (int i = 0; i < 16; ++i) tmp[i] = lds[kc + i][nr];
    short8* dstp = (short8*)(Wt + (size_t)(n0 + nr) * FIN + kc);
    dstp[0] = *(short8*)&tmp[0];
    dstp[1] = *(short8*)&tmp[8];
}

// ---------------- final GEMM (DIAGNOSTIC x4 repeat, idempotent) ----------------
// Identical to round 9 but the whole tile sweep runs GEMM_REP times so the
// dispatch rises above the harness fills in the top-5 counter table and we get
// its WRITE/FETCH/dur directly. Stores are to the same addresses every rep.

__global__ __launch_bounds__(256, 2) void k_gemm3(
    const short* __restrict__ A, const short* __restrict__ Bt,
    const float* __restrict__ bias, float* __restrict__ out) {
    __shared__ float tile[BM][68];         // 128 x 64 + pad(4) = 34,816 B
    int t = threadIdx.x;
    int w = t >> 6;
    int l = t & 63;
    int lr = l & 15;
    int lg = l >> 4;
    int mc = blockIdx.x >> 6;
    int c  = blockIdx.x & (N_CHAINS - 1);
    int nt0 = c * RUN_BASE + (c < RUN_EXTRA ? c : RUN_EXTRA);
    int cnt = RUN_BASE + (c < RUN_EXTRA ? 1 : 0);
    int m_base = mc * BM;

    short8 a[8][4];
#pragma unroll
    for (int mi = 0; mi < 8; ++mi) {
        const short* arow = A + (size_t)(m_base + mi * 16 + lr) * FIN + lg * 8;
#pragma unroll
        for (int ks = 0; ks < 4; ++ks) a[mi][ks] = *(const short8*)(arow + ks * 32);
    }

    const short* bbase = Bt + (size_t)(w * 16 + lr) * FIN + lg * 8;
    int scol = lr * 4;                     // store-phase block-local col (f32x4)

#pragma unroll 1
    for (int rep = 0; rep < GEMM_REP; ++rep) {
        short8 b0[4], b1[4];
        {
            const short* p = bbase + (size_t)nt0 * 64 * FIN;
#pragma unroll
            for (int ks = 0; ks < 4; ++ks) b0[ks] = *(const short8*)(p + ks * 32);
        }
#pragma unroll 1
        for (int i = 0; i < cnt; ++i) {
            int nt = nt0 + i;
            if (i + 1 < cnt) {
                const short* p = bbase + (size_t)(nt + 1) * 64 * FIN;
#pragma unroll
                for (int ks = 0; ks < 4; ++ks) b1[ks] = *(const short8*)(p + ks * 32);
            }
            // compute 128x64 tile -> LDS
#pragma unroll
            for (int mi = 0; mi < 8; ++mi) {
                f32x4 acc = {};
#pragma unroll
                for (int ks = 0; ks < 4; ++ks)
                    acc = __builtin_amdgcn_mfma_f32_16x16x32_bf16(b0[ks], a[mi][ks], acc, 0, 0, 0);
                *(f32x4*)&tile[mi * 16 + lr][w * 16 + lg * 4] = acc;
            }
            __syncthreads();
            // cooperative store: wave w -> rows [w*32, w*32+32), 4 rows per pass
            {
                int gcol = nt * 64 + scol;
                bool ok = gcol < N_SERVICES;
                f32x4 bv = {};
                if (ok) bv = *(const f32x4*)&bias[gcol];
                float* ob = out + (size_t)m_base * N_SERVICES + gcol;
#pragma unroll
                for (int si = 0; si < 8; ++si) {
                    int row = w * 32 + si * 4 + lg;
                    f32x4 v = *(const f32x4*)&tile[row][scol] + bv;
                    if (ok)
                        __builtin_nontemporal_store(
                            v, (f32x4*)(ob + (size_t)row * N_SERVICES));
                }
            }
            __syncthreads();
#pragma unroll
            for (int ks = 0; ks < 4; ++ks) b0[ks] = b1[ks];
        }
    }
}

// ---------------- launch ----------------

extern "C" void kernel_launch(void* const* d_in, const int* in_sizes, int n_in,
                              void* d_out, int out_size, void* d_ws, size_t ws_size,
                              hipStream_t stream) {
    const int*   user_idx    = (const int*)d_in[0];
    const int*   ctx_idx     = (const int*)d_in[1];
    const int*   ei          = (const int*)d_in[2];
    const float* user_emb    = (const float*)d_in[3];
    const float* service_emb = (const float*)d_in[4];
    const float* W1          = (const float*)d_in[5];
    const float* b1          = (const float*)d_in[6];
    const float* W2          = (const float*)d_in[7];
    const float* b2          = (const float*)d_in[8];
    const float* fcW         = (const float*)d_in[9];
    const float* fcb         = (const float*)d_in[10];
    float* out = (float*)d_out;

    const int* src = ei;
    const int* dst = ei + N_EDGES;

    char* ws = (char*)d_ws;
    float*          dis       = (float*)(ws);                    // 200,000
    unsigned short* h1        = (unsigned short*)(ws + 200000);  // 3,200,000 (bf16 h1')
    unsigned short* h2b       = (unsigned short*)(ws + 3400000); // 3,200,000 (bf16 h2')
    float*          g         = (float*)(ws + 6600000);          // 6,400,000 (g2, ctx rows only)
    unsigned short* xb        = (unsigned short*)(ws + 13000000);//   524,288
    int*            degi      = (int*)(ws + 13000000);           // 200,000 overlay (dead before k_gather)
    short*          Wt        = (short*)(ws + 13524288);         // 12,812,288
    int*            row_start = (int*)(ws + 26336576);           // 200,004
    int*            cursor    = (int*)(ws + 26536580);           // 200,000
    int*            csr_src   = (int*)(ws + 26736580);           // 6,400,000
    int*            tmp       = (int*)(ws + 26736580);           // 200,000 overlay (dead before k_fill)
    int*            blocksum  = (int*)(ws + 33136580);           // 1,024
    int*            mask      = (int*)(ws + 33137604);           // 200,000 (total ~33.3 MB)

    // cvtW also zeroes degi + mask (runs first)
    k_cvtW<<<N_PAD / 32, 256, 0, stream>>>(fcW, Wt, degi, mask);

    // CSR build (+dis in scan_block, +ctx-mask marking in scan_fin)
    k_count_degi<<<CE_BLKS, 256, 0, stream>>>(dst, degi);
    k_scan_block<<<196,  256, 0, stream>>>(degi, dis, tmp, blocksum);
    k_scan_fin  <<<196,  256, 0, stream>>>(tmp, blocksum, row_start, cursor, ctx_idx, mask);
    k_fill      <<<CE_BLKS, 256, 0, stream>>>(src, dst, cursor, csr_src);

    // layer 1 transform
    k_transform<<<6250, 256, 0, stream>>>(service_emb, W1, dis, h1);
    // fused layer-1 agg + ReLU + layer-2 transform (g1 never leaves LDS)
    k_agg_tf<<<3125, 256, 0, stream>>>(row_start, csr_src, dis,
                                       (const unsigned int*)h1, b1, W2, h2b);
    // layer-2 agg, only context nodes
    k_agg<false, true><<<3125, 256, 0, stream>>>(row_start, csr_src, dis,
                                                 (const unsigned int*)h2b, b2, mask, g);

    k_gather<<<BATCH * FIN / 256, 256, 0, stream>>>(user_idx, ctx_idx, user_emb, g, xb);

    k_gemm3<<<GEMM_BLKS, 256, 0, stream>>>((const short*)xb, Wt, fcb, out);
}

// Round 11
// 406.555 us; speedup vs baseline: 1.5630x; 1.5630x over previous
//
#include <hip/hip_runtime.h>

#define N_SERVICES 50000
#define N_PAD      50048   // 782*64
#define N_EDGES    1600000
#define N_CTX      6144    // BATCH*CONTEXT
#define EMB        32
#define BATCH      2048
#define FIN        128     // (CONTEXT+1)*EMB
#define N_TILES    782
#define BM         128
#define M_CHUNKS   16      // 2048 / BM
#define N_CHAINS   64
#define GEMM_BLKS  (M_CHUNKS * N_CHAINS)   // 1024
#define RUN_BASE   12      // 782 = 64*12 + 14 -> first 14 chains take 13 tiles
#define RUN_EXTRA  14
#define CE_BLKS    ((N_EDGES / 4 + 255) / 256)

typedef __attribute__((ext_vector_type(4))) float f32x4;
typedef __attribute__((ext_vector_type(2))) float f32x2;
typedef __attribute__((ext_vector_type(8))) short short8;

__device__ inline unsigned short f2bf(float f) {
    unsigned u = __float_as_uint(f);
    unsigned r = (u + 0x7FFFu + ((u >> 16) & 1u)) >> 16;
    return (unsigned short)r;
}
__device__ inline float bf2f(unsigned short b) {
    return __uint_as_float(((unsigned)b) << 16);
}
__device__ inline short8 f2bf8_load(const float* __restrict__ p) {
    f32x4 v0 = *(const f32x4*)p;
    f32x4 v1 = *(const f32x4*)(p + 4);
    short8 r;
    r[0] = (short)f2bf(v0[0]); r[1] = (short)f2bf(v0[1]);
    r[2] = (short)f2bf(v0[2]); r[3] = (short)f2bf(v0[3]);
    r[4] = (short)f2bf(v1[0]); r[5] = (short)f2bf(v1[1]);
    r[6] = (short)f2bf(v1[2]); r[7] = (short)f2bf(v1[3]);
    return r;
}

// ---------------- degree count (int4: 4 edges/thread) ----------------

__global__ void k_count_degi(const int* __restrict__ dst, int* __restrict__ degi) {
    int e4 = (blockIdx.x * 256 + threadIdx.x) * 4;
    if (e4 < N_EDGES) {            // N_EDGES%4==0: all-or-nothing
        int4 d = *(const int4*)(dst + e4);
        atomicAdd(&degi[d.x], 1);
        atomicAdd(&degi[d.y], 1);
        atomicAdd(&degi[d.z], 1);
        atomicAdd(&degi[d.w], 1);
    }
}

// ---------------- prefix scan (2 kernels); dis folded in ----------------

__global__ void k_scan_block(const int* __restrict__ degi, float* __restrict__ dis,
                             int* __restrict__ tmp, int* __restrict__ blocksum) {
    __shared__ int s[256];
    int t = threadIdx.x, i = blockIdx.x * 256 + t;
    int v = (i < N_SERVICES) ? degi[i] : 0;
    if (i < N_SERVICES) dis[i] = rsqrtf((float)(v + 1));  // +1 self-loop
    s[t] = v;
    __syncthreads();
#pragma unroll
    for (int o = 1; o < 256; o <<= 1) {
        int x = 0;
        if (t >= o) x = s[t - o];
        __syncthreads();
        if (t >= o) s[t] += x;
        __syncthreads();
    }
    if (i < N_SERVICES) tmp[i] = s[t] - v;       // exclusive within block
    if (t == 255) blocksum[blockIdx.x] = s[255];
}

// merged: scan the 196 block sums redundantly per block, finish row_start/cursor,
// and mark the context-node mask (mask zeroed earlier in k_cvtW)
__global__ void k_scan_fin(const int* __restrict__ tmp, const int* __restrict__ blocksum,
                           int* __restrict__ row_start, int* __restrict__ cursor,
                           const int* __restrict__ ctx_idx, int* __restrict__ mask) {
    __shared__ int s[256];
    int t = threadIdx.x;
    int v = (t < 196) ? blocksum[t] : 0;
    s[t] = v;
    __syncthreads();
#pragma unroll
    for (int o = 1; o < 256; o <<= 1) {
        int x = 0;
        if (t >= o) x = s[t - o];
        __syncthreads();
        if (t >= o) s[t] += x;
        __syncthreads();
    }
    int prefix = (blockIdx.x == 0) ? 0 : s[blockIdx.x - 1];  // exclusive block prefix
    int i = blockIdx.x * 256 + t;
    if (i < N_SERVICES) {
        int r = tmp[i] + prefix;
        row_start[i] = r;
        cursor[i] = r;
    }
    if (i < N_CTX) mask[ctx_idx[i]] = 1;
    if (i == 0) row_start[N_SERVICES] = N_EDGES;
}

// ---------------- CSR fill (int4: 4 edges/thread) ----------------

__global__ void k_fill(const int* __restrict__ src, const int* __restrict__ dst,
                       int* __restrict__ cursor, int* __restrict__ csr_src) {
    int e4 = (blockIdx.x * 256 + threadIdx.x) * 4;
    if (e4 < N_EDGES) {
        int4 s = *(const int4*)(src + e4);
        int4 d = *(const int4*)(dst + e4);
        csr_src[atomicAdd(&cursor[d.x], 1)] = s.x;
        csr_src[atomicAdd(&cursor[d.y], 1)] = s.y;
        csr_src[atomicAdd(&cursor[d.z], 1)] = s.z;
        csr_src[atomicAdd(&cursor[d.w], 1)] = s.w;
    }
}

// ---------------- GCN pieces ----------------

// h' (bf16) = (in @ W) * dis[node]   — dis pre-multiplied so agg is a plain sum
__global__ void k_transform(const float* __restrict__ in, const float* __restrict__ W,
                            const float* __restrict__ dis, unsigned short* __restrict__ h) {
    __shared__ float Ws[EMB][EMB + 1];
    __shared__ float rows[8][EMB];
    int t = threadIdx.x;
    int j = t & 31, li = t >> 5;
    for (int i = t; i < EMB * EMB; i += 256) Ws[i >> 5][i & 31] = W[i];
    int node = blockIdx.x * 8 + li;
    if (node < N_SERVICES) rows[li][j] = in[node * EMB + j];
    __syncthreads();
    if (node < N_SERVICES) {
        float acc = 0.f;
#pragma unroll
        for (int k = 0; k < EMB; ++k) acc = fmaf(rows[li][k], Ws[k][j], acc);
        h[node * EMB + j] = f2bf(acc * dis[node]);
    }
}

// Fused layer-1 agg + ReLU + layer-2 transform:
//   g1[n][:] = relu(dis[n]*(Σ_{s∈N(n)} h1'[s] + h1'[n]) + b1)   (kept in LDS only)
//   h2'[n][:] = (g1[n][:] @ W2) * dis[n]                        (bf16 out)
__global__ __launch_bounds__(256) void k_agg_tf(
    const int* __restrict__ row_start, const int* __restrict__ csr_src,
    const float* __restrict__ dis, const unsigned int* __restrict__ h2,
    const float* __restrict__ b, const float* __restrict__ W2,
    unsigned short* __restrict__ hout) {
    __shared__ float gr[16][33];
    __shared__ float Ws[32][33];
    int t = threadIdx.x;
    for (int i = t; i < EMB * EMB; i += 256) Ws[i >> 5][i & 31] = W2[i];

    int j2 = t & 15;                       // dim pair
    int local = t >> 4;
    int node = blockIdx.x * 16 + local;
    int e = row_start[node], e1 = row_start[node + 1];
    float al0 = 0.f, ah0 = 0.f, al1 = 0.f, ah1 = 0.f;
    float al2 = 0.f, ah2 = 0.f, al3 = 0.f, ah3 = 0.f;
    for (; e + 4 <= e1; e += 4) {
        int s0 = csr_src[e], s1 = csr_src[e + 1], s2 = csr_src[e + 2], s3 = csr_src[e + 3];
        unsigned v0 = h2[s0 * 16 + j2], v1 = h2[s1 * 16 + j2];
        unsigned v2 = h2[s2 * 16 + j2], v3 = h2[s3 * 16 + j2];
        al0 += bf2f((unsigned short)(v0 & 0xffff)); ah0 += bf2f((unsigned short)(v0 >> 16));
        al1 += bf2f((unsigned short)(v1 & 0xffff)); ah1 += bf2f((unsigned short)(v1 >> 16));
        al2 += bf2f((unsigned short)(v2 & 0xffff)); ah2 += bf2f((unsigned short)(v2 >> 16));
        al3 += bf2f((unsigned short)(v3 & 0xffff)); ah3 += bf2f((unsigned short)(v3 >> 16));
    }
    for (; e < e1; ++e) {
        unsigned v0 = h2[csr_src[e] * 16 + j2];
        al0 += bf2f((unsigned short)(v0 & 0xffff)); ah0 += bf2f((unsigned short)(v0 >> 16));
    }
    float dn = dis[node];
    unsigned vn = h2[node * 16 + j2];
    float lo = dn * ((al0 + al1) + (al2 + al3) + bf2f((unsigned short)(vn & 0xffff))) + b[j2 * 2];
    float hi = dn * ((ah0 + ah1) + (ah2 + ah3) + bf2f((unsigned short)(vn >> 16))) + b[j2 * 2 + 1];
    gr[local][j2 * 2]     = fmaxf(lo, 0.f);
    gr[local][j2 * 2 + 1] = fmaxf(hi, 0.f);
    __syncthreads();

    // phase 2: transform the block's 16 g1 rows by W2; 2 nodes per thread
    int d = t & 31;
    int l0 = t >> 5;                       // 0..7
    float s0 = 0.f, s1 = 0.f;
#pragma unroll
    for (int k = 0; k < EMB; ++k) {
        float w = Ws[k][d];
        s0 = fmaf(gr[l0][k], w, s0);
        s1 = fmaf(gr[l0 + 8][k], w, s1);
    }
    int n0 = blockIdx.x * 16 + l0;
    hout[(size_t)n0 * EMB + d]       = f2bf(s0 * dis[n0]);
    hout[(size_t)(n0 + 8) * EMB + d] = f2bf(s1 * dis[n0 + 8]);
}

// layer-2 aggregation, masked to context nodes
template <bool RELU, bool MASKED>
__global__ void k_agg(const int* __restrict__ row_start, const int* __restrict__ csr_src,
                      const float* __restrict__ dis, const unsigned int* __restrict__ h2,
                      const float* __restrict__ b, const int* __restrict__ mask,
                      float* __restrict__ out) {
    int t = threadIdx.x;
    int j2 = t & 15;                       // dim pair
    int node = blockIdx.x * 16 + (t >> 4);
    if (node >= N_SERVICES) return;
    if (MASKED && !mask[node]) return;
    int e = row_start[node], e1 = row_start[node + 1];
    float al0 = 0.f, ah0 = 0.f, al1 = 0.f, ah1 = 0.f;
    float al2 = 0.f, ah2 = 0.f, al3 = 0.f, ah3 = 0.f;
    for (; e + 4 <= e1; e += 4) {
        int s0 = csr_src[e], s1 = csr_src[e + 1], s2 = csr_src[e + 2], s3 = csr_src[e + 3];
        unsigned v0 = h2[s0 * 16 + j2], v1 = h2[s1 * 16 + j2];
        unsigned v2 = h2[s2 * 16 + j2], v3 = h2[s3 * 16 + j2];
        al0 += bf2f((unsigned short)(v0 & 0xffff)); ah0 += bf2f((unsigned short)(v0 >> 16));
        al1 += bf2f((unsigned short)(v1 & 0xffff)); ah1 += bf2f((unsigned short)(v1 >> 16));
        al2 += bf2f((unsigned short)(v2 & 0xffff)); ah2 += bf2f((unsigned short)(v2 >> 16));
        al3 += bf2f((unsigned short)(v3 & 0xffff)); ah3 += bf2f((unsigned short)(v3 >> 16));
    }
    for (; e < e1; ++e) {
        unsigned v0 = h2[csr_src[e] * 16 + j2];
        al0 += bf2f((unsigned short)(v0 & 0xffff)); ah0 += bf2f((unsigned short)(v0 >> 16));
    }
    float dn = dis[node];
    unsigned vn = h2[node * 16 + j2];
    float lo = dn * ((al0 + al1) + (al2 + al3) + bf2f((unsigned short)(vn & 0xffff))) + b[j2 * 2];
    float hi = dn * ((ah0 + ah1) + (ah2 + ah3) + bf2f((unsigned short)(vn >> 16))) + b[j2 * 2 + 1];
    if (RELU) { lo = fmaxf(lo, 0.f); hi = fmaxf(hi, 0.f); }
    f32x2 o; o.x = lo; o.y = hi;
    *(f32x2*)&out[node * EMB + j2 * 2] = o;
}

// ---------------- fc_W transpose+convert + zero degi/mask ----------------

__global__ __launch_bounds__(256) void k_cvtW(const float* __restrict__ W,
                                              short* __restrict__ Wt,
                                              int* __restrict__ degi,
                                              int* __restrict__ mask) {
    int gid = blockIdx.x * 256 + threadIdx.x;
    if (gid < N_SERVICES) { degi[gid] = 0; mask[gid] = 0; }

    __shared__ short lds[128][33];
    int t = threadIdx.x;
    int n0 = blockIdx.x * 32;
    int nx = t & 31;
    int n  = n0 + nx;
    int kg = t >> 5;                 // 0..7
#pragma unroll
    for (int r = 0; r < 16; ++r) {
        int k = r * 8 + kg;
        float v = (n < N_SERVICES) ? W[k * N_SERVICES + n] : 0.f;
        lds[k][nx] = (short)f2bf(v);
    }
    __syncthreads();
    int nr = t >> 3;                 // 0..31
    int kc = (t & 7) * 16;
    short tmp[16];
#pragma unroll
    for (int i = 0; i < 16; ++i) tmp[i] = lds[kc + i][nr];
    short8* dstp = (short8*)(Wt + (size_t)(n0 + nr) * FIN + kc);
    dstp[0] = *(short8*)&tmp[0];
    dstp[1] = *(short8*)&tmp[8];
}

// ---------------- final GEMM: fused gather + double-buffered LDS stores ----------
// A-fragments built in-kernel from user_emb/g via index arrays (k_gather fused).
// LDS tile double-buffered: ONE barrier per iteration -> global stores of tile p
// drain during the next iteration's MFMA phase instead of at an immediate barrier.
// Normal (cached) stores instead of nontemporal.

__global__ __launch_bounds__(256, 2) void k_gemm3(
    const int* __restrict__ user_idx, const int* __restrict__ ctx_idx,
    const float* __restrict__ user_emb, const float* __restrict__ g,
    const short* __restrict__ Bt, const float* __restrict__ bias,
    float* __restrict__ out) {
    __shared__ float tile[2][BM][68];      // 2 x 34,816 B
    int t = threadIdx.x;
    int w = t >> 6;
    int l = t & 63;
    int lr = l & 15;
    int lg = l >> 4;
    int mc = blockIdx.x >> 6;
    int c  = blockIdx.x & (N_CHAINS - 1);
    int nt0 = c * RUN_BASE + (c < RUN_EXTRA ? c : RUN_EXTRA);
    int cnt = RUN_BASE + (c < RUN_EXTRA ? 1 : 0);
    int m_base = mc * BM;

    // A fragments: gather + f32->bf16 convert, once per block
    short8 a[8][4];
#pragma unroll
    for (int mi = 0; mi < 8; ++mi) {
        int row = m_base + mi * 16 + lr;
        a[mi][0] = f2bf8_load(user_emb + (size_t)user_idx[row] * EMB + lg * 8);
#pragma unroll
        for (int ks = 1; ks < 4; ++ks)
            a[mi][ks] = f2bf8_load(g + (size_t)ctx_idx[row * 3 + ks - 1] * EMB + lg * 8);
    }

    const short* bbase = Bt + (size_t)(w * 16 + lr) * FIN + lg * 8;
    short8 b0[4], b1[4];
    {
        const short* p = bbase + (size_t)nt0 * 64 * FIN;
#pragma unroll
        for (int ks = 0; ks < 4; ++ks) b0[ks] = *(const short8*)(p + ks * 32);
    }

    int scol = lr * 4;                     // store-phase block-local col (f32x4)
    int p = 0;

    for (int i = 0; i < cnt; ++i) {
        int nt = nt0 + i;
        if (i + 1 < cnt) {
            const short* pp = bbase + (size_t)(nt + 1) * 64 * FIN;
#pragma unroll
            for (int ks = 0; ks < 4; ++ks) b1[ks] = *(const short8*)(pp + ks * 32);
        }
        // compute 128x64 tile -> LDS buf p
#pragma unroll
        for (int mi = 0; mi < 8; ++mi) {
            f32x4 acc = {};
#pragma unroll
            for (int ks = 0; ks < 4; ++ks)
                acc = __builtin_amdgcn_mfma_f32_16x16x32_bf16(b0[ks], a[mi][ks], acc, 0, 0, 0);
            *(f32x4*)&tile[p][mi * 16 + lr][w * 16 + lg * 4] = acc;
        }
        __syncthreads();                   // single barrier per iteration
        // cooperative store from buf p; drains during next iter's MFMA phase
        {
            int gcol = nt * 64 + scol;
            bool ok = gcol < N_SERVICES;   // 50000%4==0: f32x4 all-in or all-out
            f32x4 bv = {};
            if (ok) bv = *(const f32x4*)&bias[gcol];
            float* ob = out + (size_t)m_base * N_SERVICES + gcol;
#pragma unroll
            for (int si = 0; si < 8; ++si) {
                int row = w * 32 + si * 4 + lg;
                f32x4 v = *(const f32x4*)&tile[p][row][scol] + bv;
                if (ok) *(f32x4*)(ob + (size_t)row * N_SERVICES) = v;
            }
        }
        p ^= 1;
#pragma unroll
        for (int ks = 0; ks < 4; ++ks) b0[ks] = b1[ks];
    }
}

// ---------------- launch ----------------

extern "C" void kernel_launch(void* const* d_in, const int* in_sizes, int n_in,
                              void* d_out, int out_size, void* d_ws, size_t ws_size,
                              hipStream_t stream) {
    const int*   user_idx    = (const int*)d_in[0];
    const int*   ctx_idx     = (const int*)d_in[1];
    const int*   ei          = (const int*)d_in[2];
    const float* user_emb    = (const float*)d_in[3];
    const float* service_emb = (const float*)d_in[4];
    const float* W1          = (const float*)d_in[5];
    const float* b1          = (const float*)d_in[6];
    const float* W2          = (const float*)d_in[7];
    const float* b2          = (const float*)d_in[8];
    const float* fcW         = (const float*)d_in[9];
    const float* fcb         = (const float*)d_in[10];
    float* out = (float*)d_out;

    const int* src = ei;
    const int* dst = ei + N_EDGES;

    char* ws = (char*)d_ws;
    float*          dis       = (float*)(ws);                    // 200,000
    unsigned short* h1        = (unsigned short*)(ws + 200000);  // 3,200,000 (bf16 h1')
    unsigned short* h2b       = (unsigned short*)(ws + 3400000); // 3,200,000 (bf16 h2')
    float*          g         = (float*)(ws + 6600000);          // 6,400,000 (g2, ctx rows only)
    int*            degi      = (int*)(ws + 13000000);           // 200,000
    short*          Wt        = (short*)(ws + 13524288);         // 12,812,288
    int*            row_start = (int*)(ws + 26336576);           // 200,004
    int*            cursor    = (int*)(ws + 26536580);           // 200,000
    int*            csr_src   = (int*)(ws + 26736580);           // 6,400,000
    int*            tmp       = (int*)(ws + 26736580);           // 200,000 overlay (dead before k_fill)
    int*            blocksum  = (int*)(ws + 33136580);           // 1,024
    int*            mask      = (int*)(ws + 33137604);           // 200,000 (total ~33.3 MB)

    // cvtW also zeroes degi + mask (runs first)
    k_cvtW<<<N_PAD / 32, 256, 0, stream>>>(fcW, Wt, degi, mask);

    // CSR build (+dis in scan_block, +ctx-mask marking in scan_fin)
    k_count_degi<<<CE_BLKS, 256, 0, stream>>>(dst, degi);
    k_scan_block<<<196,  256, 0, stream>>>(degi, dis, tmp, blocksum);
    k_scan_fin  <<<196,  256, 0, stream>>>(tmp, blocksum, row_start, cursor, ctx_idx, mask);
    k_fill      <<<CE_BLKS, 256, 0, stream>>>(src, dst, cursor, csr_src);

    // layer 1 transform
    k_transform<<<6250, 256, 0, stream>>>(service_emb, W1, dis, h1);
    // fused layer-1 agg + ReLU + layer-2 transform (g1 never leaves LDS)
    k_agg_tf<<<3125, 256, 0, stream>>>(row_start, csr_src, dis,
                                       (const unsigned int*)h1, b1, W2, h2b);
    // layer-2 agg, only context nodes
    k_agg<false, true><<<3125, 256, 0, stream>>>(row_start, csr_src, dis,
                                                 (const unsigned int*)h2b, b2, mask, g);

    // final GEMM (gather fused into A-setup)
    k_gemm3<<<GEMM_BLKS, 256, 0, stream>>>(user_idx, ctx_idx, user_emb, g,
                                           Wt, fcb, out);
}

// Round 12
// 352.871 us; speedup vs baseline: 1.8008x; 1.1521x over previous
//
#include <hip/hip_runtime.h>

#define N_SERVICES 50000
#define N_PAD      50048   // 782*64
#define N_EDGES    1600000
#define N_CTX      6144    // BATCH*CONTEXT
#define EMB        32
#define BATCH      2048
#define FIN        128     // (CONTEXT+1)*EMB
#define N_TILES    782
#define BM         128
#define M_CHUNKS   16      // 2048 / BM
#define N_CHAINS   64
#define GEMM_BLKS  (M_CHUNKS * N_CHAINS)   // 1024
#define RUN_BASE   12      // 782 = 64*12 + 14 -> first 14 chains take 13 tiles
#define RUN_EXTRA  14
#define CE_BLKS    ((N_EDGES / 4 + 255) / 256)

typedef __attribute__((ext_vector_type(4))) float f32x4;
typedef __attribute__((ext_vector_type(2))) float f32x2;
typedef __attribute__((ext_vector_type(8))) short short8;

__device__ inline unsigned short f2bf(float f) {
    unsigned u = __float_as_uint(f);
    unsigned r = (u + 0x7FFFu + ((u >> 16) & 1u)) >> 16;
    return (unsigned short)r;
}
__device__ inline float bf2f(unsigned short b) {
    return __uint_as_float(((unsigned)b) << 16);
}

// ---------------- degree count (int4: 4 edges/thread) ----------------

__global__ void k_count_degi(const int* __restrict__ dst, int* __restrict__ degi) {
    int e4 = (blockIdx.x * 256 + threadIdx.x) * 4;
    if (e4 < N_EDGES) {            // N_EDGES%4==0: all-or-nothing
        int4 d = *(const int4*)(dst + e4);
        atomicAdd(&degi[d.x], 1);
        atomicAdd(&degi[d.y], 1);
        atomicAdd(&degi[d.z], 1);
        atomicAdd(&degi[d.w], 1);
    }
}

// ---------------- scan pass 1; dis folded in ----------------

__global__ void k_scan_block(const int* __restrict__ degi, float* __restrict__ dis,
                             int* __restrict__ tmp, int* __restrict__ blocksum) {
    __shared__ int s[256];
    int t = threadIdx.x, i = blockIdx.x * 256 + t;
    int v = (i < N_SERVICES) ? degi[i] : 0;
    if (i < N_SERVICES) dis[i] = rsqrtf((float)(v + 1));  // +1 self-loop
    s[t] = v;
    __syncthreads();
#pragma unroll
    for (int o = 1; o < 256; o <<= 1) {
        int x = 0;
        if (t >= o) x = s[t - o];
        __syncthreads();
        if (t >= o) s[t] += x;
        __syncthreads();
    }
    if (i < N_SERVICES) tmp[i] = s[t] - v;       // exclusive within block
    if (t == 255) blocksum[blockIdx.x] = s[255];
}

// ---------------- fused: scan finish (+ctx list build)  ∥  layer-1 transform ----
// blocks 0..195: finish row_start/cursor, build compact ctx_list with atomicExch
// dedup. blocks 196..6445: h1' = (service_emb @ W1)*dis  (bf16).

__global__ __launch_bounds__(256) void k_scanfin_tf(
    const int* __restrict__ tmp, const int* __restrict__ blocksum,
    int* __restrict__ row_start, int* __restrict__ cursor,
    const int* __restrict__ ctx_idx, int* __restrict__ mask,
    int* __restrict__ ctx_list, int* __restrict__ ctx_count,
    const float* __restrict__ in, const float* __restrict__ W1,
    const float* __restrict__ dis, unsigned short* __restrict__ h) {
    __shared__ int s[256];
    __shared__ float Ws[EMB][EMB + 1];
    __shared__ float rows[8][EMB];
    int t = threadIdx.x;

    if (blockIdx.x < 196) {
        int v = (t < 196) ? blocksum[t] : 0;
        s[t] = v;
        __syncthreads();
#pragma unroll
        for (int o = 1; o < 256; o <<= 1) {
            int x = 0;
            if (t >= o) x = s[t - o];
            __syncthreads();
            if (t >= o) s[t] += x;
            __syncthreads();
        }
        int prefix = (blockIdx.x == 0) ? 0 : s[blockIdx.x - 1];
        int i = blockIdx.x * 256 + t;
        if (i < N_SERVICES) {
            int r = tmp[i] + prefix;
            row_start[i] = r;
            cursor[i] = r;
        }
        if (i < N_CTX) {
            int n = ctx_idx[i];
            if (atomicExch(&mask[n], 1) == 0)
                ctx_list[atomicAdd(ctx_count, 1)] = n;
        }
        if (i == 0) row_start[N_SERVICES] = N_EDGES;
    } else {
        int j = t & 31, li = t >> 5;
        for (int i = t; i < EMB * EMB; i += 256) Ws[i >> 5][i & 31] = W1[i];
        int node = (blockIdx.x - 196) * 8 + li;
        if (node < N_SERVICES) rows[li][j] = in[node * EMB + j];
        __syncthreads();
        if (node < N_SERVICES) {
            float acc = 0.f;
#pragma unroll
            for (int k = 0; k < EMB; ++k) acc = fmaf(rows[li][k], Ws[k][j], acc);
            h[node * EMB + j] = f2bf(acc * dis[node]);
        }
    }
}

// ---------------- CSR fill (int4: 4 edges/thread) ----------------

__global__ void k_fill(const int* __restrict__ src, const int* __restrict__ dst,
                       int* __restrict__ cursor, int* __restrict__ csr_src) {
    int e4 = (blockIdx.x * 256 + threadIdx.x) * 4;
    if (e4 < N_EDGES) {
        int4 s = *(const int4*)(src + e4);
        int4 d = *(const int4*)(dst + e4);
        csr_src[atomicAdd(&cursor[d.x], 1)] = s.x;
        csr_src[atomicAdd(&cursor[d.y], 1)] = s.y;
        csr_src[atomicAdd(&cursor[d.z], 1)] = s.z;
        csr_src[atomicAdd(&cursor[d.w], 1)] = s.w;
    }
}

// ---------------- fused layer-1 agg + ReLU + layer-2 transform ----------------
//   g1[n][:] = relu(dis[n]*(Σ_{s∈N(n)} h1'[s] + h1'[n]) + b1)   (LDS only)
//   h2'[n][:] = (g1[n][:] @ W2) * dis[n]                        (bf16 out)
__global__ __launch_bounds__(256) void k_agg_tf(
    const int* __restrict__ row_start, const int* __restrict__ csr_src,
    const float* __restrict__ dis, const unsigned int* __restrict__ h2,
    const float* __restrict__ b, const float* __restrict__ W2,
    unsigned short* __restrict__ hout) {
    __shared__ float gr[16][33];
    __shared__ float Ws[32][33];
    int t = threadIdx.x;
    for (int i = t; i < EMB * EMB; i += 256) Ws[i >> 5][i & 31] = W2[i];

    int j2 = t & 15;                       // dim pair
    int local = t >> 4;
    int node = blockIdx.x * 16 + local;
    int e = row_start[node], e1 = row_start[node + 1];
    float al0 = 0.f, ah0 = 0.f, al1 = 0.f, ah1 = 0.f;
    float al2 = 0.f, ah2 = 0.f, al3 = 0.f, ah3 = 0.f;
    for (; e + 4 <= e1; e += 4) {
        int s0 = csr_src[e], s1 = csr_src[e + 1], s2 = csr_src[e + 2], s3 = csr_src[e + 3];
        unsigned v0 = h2[s0 * 16 + j2], v1 = h2[s1 * 16 + j2];
        unsigned v2 = h2[s2 * 16 + j2], v3 = h2[s3 * 16 + j2];
        al0 += bf2f((unsigned short)(v0 & 0xffff)); ah0 += bf2f((unsigned short)(v0 >> 16));
        al1 += bf2f((unsigned short)(v1 & 0xffff)); ah1 += bf2f((unsigned short)(v1 >> 16));
        al2 += bf2f((unsigned short)(v2 & 0xffff)); ah2 += bf2f((unsigned short)(v2 >> 16));
        al3 += bf2f((unsigned short)(v3 & 0xffff)); ah3 += bf2f((unsigned short)(v3 >> 16));
    }
    for (; e < e1; ++e) {
        unsigned v0 = h2[csr_src[e] * 16 + j2];
        al0 += bf2f((unsigned short)(v0 & 0xffff)); ah0 += bf2f((unsigned short)(v0 >> 16));
    }
    float dn = dis[node];
    unsigned vn = h2[node * 16 + j2];
    float lo = dn * ((al0 + al1) + (al2 + al3) + bf2f((unsigned short)(vn & 0xffff))) + b[j2 * 2];
    float hi = dn * ((ah0 + ah1) + (ah2 + ah3) + bf2f((unsigned short)(vn >> 16))) + b[j2 * 2 + 1];
    gr[local][j2 * 2]     = fmaxf(lo, 0.f);
    gr[local][j2 * 2 + 1] = fmaxf(hi, 0.f);
    __syncthreads();

    // phase 2: transform the block's 16 g1 rows by W2; 2 nodes per thread
    int d = t & 31;
    int l0 = t >> 5;                       // 0..7
    float s0 = 0.f, s1 = 0.f;
#pragma unroll
    for (int k = 0; k < EMB; ++k) {
        float w = Ws[k][d];
        s0 = fmaf(gr[l0][k], w, s0);
        s1 = fmaf(gr[l0 + 8][k], w, s1);
    }
    int n0 = blockIdx.x * 16 + l0;
    hout[(size_t)n0 * EMB + d]       = f2bf(s0 * dis[n0]);
    hout[(size_t)(n0 + 8) * EMB + d] = f2bf(s1 * dis[n0 + 8]);
}

// ---------------- layer-2 agg over the compact ctx list ----------------
// 384 blocks x 16 slots = 6144; slots >= count exit. Duplicate-free via mask.

__global__ void k_agg_ctx(const int* __restrict__ row_start, const int* __restrict__ csr_src,
                          const float* __restrict__ dis, const unsigned int* __restrict__ h2,
                          const float* __restrict__ b, const int* __restrict__ ctx_list,
                          const int* __restrict__ ctx_count, float* __restrict__ out) {
    int t = threadIdx.x;
    int j2 = t & 15;
    int slot = blockIdx.x * 16 + (t >> 4);
    if (slot >= *ctx_count) return;
    int node = ctx_list[slot];
    int e = row_start[node], e1 = row_start[node + 1];
    float al0 = 0.f, ah0 = 0.f, al1 = 0.f, ah1 = 0.f;
    float al2 = 0.f, ah2 = 0.f, al3 = 0.f, ah3 = 0.f;
    for (; e + 4 <= e1; e += 4) {
        int s0 = csr_src[e], s1 = csr_src[e + 1], s2 = csr_src[e + 2], s3 = csr_src[e + 3];
        unsigned v0 = h2[s0 * 16 + j2], v1 = h2[s1 * 16 + j2];
        unsigned v2 = h2[s2 * 16 + j2], v3 = h2[s3 * 16 + j2];
        al0 += bf2f((unsigned short)(v0 & 0xffff)); ah0 += bf2f((unsigned short)(v0 >> 16));
        al1 += bf2f((unsigned short)(v1 & 0xffff)); ah1 += bf2f((unsigned short)(v1 >> 16));
        al2 += bf2f((unsigned short)(v2 & 0xffff)); ah2 += bf2f((unsigned short)(v2 >> 16));
        al3 += bf2f((unsigned short)(v3 & 0xffff)); ah3 += bf2f((unsigned short)(v3 >> 16));
    }
    for (; e < e1; ++e) {
        unsigned v0 = h2[csr_src[e] * 16 + j2];
        al0 += bf2f((unsigned short)(v0 & 0xffff)); ah0 += bf2f((unsigned short)(v0 >> 16));
    }
    float dn = dis[node];
    unsigned vn = h2[node * 16 + j2];
    float lo = dn * ((al0 + al1) + (al2 + al3) + bf2f((unsigned short)(vn & 0xffff))) + b[j2 * 2];
    float hi = dn * ((ah0 + ah1) + (ah2 + ah3) + bf2f((unsigned short)(vn >> 16))) + b[j2 * 2 + 1];
    f32x2 o; o.x = lo; o.y = hi;
    *(f32x2*)&out[node * EMB + j2 * 2] = o;
}

// ---------------- feature gather (emit bf16) ----------------

__global__ void k_gather(const int* __restrict__ user_idx, const int* __restrict__ ctx_idx,
                         const float* __restrict__ user_emb, const float* __restrict__ g2,
                         unsigned short* __restrict__ x) {
    int t = blockIdx.x * 256 + threadIdx.x;  // grid exact: BATCH*FIN
    int b = t >> 7, p = t & 127;
    float v;
    if (p < EMB) {
        v = user_emb[user_idx[b] * EMB + p];
    } else {
        int c = (p - EMB) >> 5, j = p & 31;
        v = g2[ctx_idx[b * 3 + c] * EMB + j];
    }
    x[t] = f2bf(v);
}

// ---------------- fc_W transpose+convert + zero degi/mask/ctx_count ----------------

__global__ __launch_bounds__(256) void k_cvtW(const float* __restrict__ W,
                                              short* __restrict__ Wt,
                                              int* __restrict__ degi,
                                              int* __restrict__ mask,
                                              int* __restrict__ ctx_count) {
    int gid = blockIdx.x * 256 + threadIdx.x;
    if (gid < N_SERVICES) { degi[gid] = 0; mask[gid] = 0; }
    if (gid == 0) *ctx_count = 0;

    __shared__ short lds[128][33];
    int t = threadIdx.x;
    int n0 = blockIdx.x * 32;
    int nx = t & 31;
    int n  = n0 + nx;
    int kg = t >> 5;                 // 0..7
#pragma unroll
    for (int r = 0; r < 16; ++r) {
        int k = r * 8 + kg;
        float v = (n < N_SERVICES) ? W[k * N_SERVICES + n] : 0.f;
        lds[k][nx] = (short)f2bf(v);
    }
    __syncthreads();
    int nr = t >> 3;                 // 0..31
    int kc = (t & 7) * 16;
    short tmp[16];
#pragma unroll
    for (int i = 0; i < 16; ++i) tmp[i] = lds[kc + i][nr];
    short8* dstp = (short8*)(Wt + (size_t)(n0 + nr) * FIN + kc);
    dstp[0] = *(short8*)&tmp[0];
    dstp[1] = *(short8*)&tmp[8];
}

// ---------------- final GEMM: persistent, BM=128 in regs, dbuf LDS, NT stores ----
// r9/r10-measured config (NT stores, separate gather) + single-barrier double
// buffer: stores of tile p drain during the next iteration's MFMA phase.

__global__ __launch_bounds__(256, 2) void k_gemm3(
    const short* __restrict__ A, const short* __restrict__ Bt,
    const float* __restrict__ bias, float* __restrict__ out) {
    __shared__ float tile[2][BM][68];      // 2 x 34,816 B
    int t = threadIdx.x;
    int w = t >> 6;
    int l = t & 63;
    int lr = l & 15;
    int lg = l >> 4;
    int mc = blockIdx.x >> 6;
    int c  = blockIdx.x & (N_CHAINS - 1);
    int nt0 = c * RUN_BASE + (c < RUN_EXTRA ? c : RUN_EXTRA);
    int cnt = RUN_BASE + (c < RUN_EXTRA ? 1 : 0);
    int m_base = mc * BM;

    short8 a[8][4];
#pragma unroll
    for (int mi = 0; mi < 8; ++mi) {
        const short* arow = A + (size_t)(m_base + mi * 16 + lr) * FIN + lg * 8;
#pragma unroll
        for (int ks = 0; ks < 4; ++ks) a[mi][ks] = *(const short8*)(arow + ks * 32);
    }

    const short* bbase = Bt + (size_t)(w * 16 + lr) * FIN + lg * 8;
    short8 b0[4], b1[4];
    {
        const short* p = bbase + (size_t)nt0 * 64 * FIN;
#pragma unroll
        for (int ks = 0; ks < 4; ++ks) b0[ks] = *(const short8*)(p + ks * 32);
    }

    int scol = lr * 4;                     // store-phase block-local col (f32x4)
    int p = 0;

    for (int i = 0; i < cnt; ++i) {
        int nt = nt0 + i;
        if (i + 1 < cnt) {
            const short* pp = bbase + (size_t)(nt + 1) * 64 * FIN;
#pragma unroll
            for (int ks = 0; ks < 4; ++ks) b1[ks] = *(const short8*)(pp + ks * 32);
        }
        // compute 128x64 tile -> LDS buf p
#pragma unroll
        for (int mi = 0; mi < 8; ++mi) {
            f32x4 acc = {};
#pragma unroll
            for (int ks = 0; ks < 4; ++ks)
                acc = __builtin_amdgcn_mfma_f32_16x16x32_bf16(b0[ks], a[mi][ks], acc, 0, 0, 0);
            *(f32x4*)&tile[p][mi * 16 + lr][w * 16 + lg * 4] = acc;
        }
        __syncthreads();                   // single barrier per iteration
        // cooperative NT store from buf p; drains during next iter's MFMA phase
        {
            int gcol = nt * 64 + scol;
            bool ok = gcol < N_SERVICES;   // 50000%4==0: f32x4 all-in or all-out
            f32x4 bv = {};
            if (ok) bv = *(const f32x4*)&bias[gcol];
            float* ob = out + (size_t)m_base * N_SERVICES + gcol;
#pragma unroll
            for (int si = 0; si < 8; ++si) {
                int row = w * 32 + si * 4 + lg;
                f32x4 v = *(const f32x4*)&tile[p][row][scol] + bv;
                if (ok)
                    __builtin_nontemporal_store(
                        v, (f32x4*)(ob + (size_t)row * N_SERVICES));
            }
        }
        p ^= 1;
#pragma unroll
        for (int ks = 0; ks < 4; ++ks) b0[ks] = b1[ks];
    }
}

// ---------------- launch ----------------

extern "C" void kernel_launch(void* const* d_in, const int* in_sizes, int n_in,
                              void* d_out, int out_size, void* d_ws, size_t ws_size,
                              hipStream_t stream) {
    const int*   user_idx    = (const int*)d_in[0];
    const int*   ctx_idx     = (const int*)d_in[1];
    const int*   ei          = (const int*)d_in[2];
    const float* user_emb    = (const float*)d_in[3];
    const float* service_emb = (const float*)d_in[4];
    const float* W1          = (const float*)d_in[5];
    const float* b1          = (const float*)d_in[6];
    const float* W2          = (const float*)d_in[7];
    const float* b2          = (const float*)d_in[8];
    const float* fcW         = (const float*)d_in[9];
    const float* fcb         = (const float*)d_in[10];
    float* out = (float*)d_out;

    const int* src = ei;
    const int* dst = ei + N_EDGES;

    char* ws = (char*)d_ws;
    float*          dis       = (float*)(ws);                    // 200,000
    unsigned short* h1        = (unsigned short*)(ws + 200000);  // 3,200,000 (bf16 h1')
    unsigned short* h2b       = (unsigned short*)(ws + 3400000); // 3,200,000 (bf16 h2')
    float*          g         = (float*)(ws + 6600000);          // 6,400,000 (g2, ctx rows only)
    unsigned short* xb        = (unsigned short*)(ws + 13000000);//   524,288
    int*            degi      = (int*)(ws + 13000000);           // 200,000 overlay (dead before k_gather)
    short*          Wt        = (short*)(ws + 13524288);         // 12,812,288
    int*            row_start = (int*)(ws + 26336576);           // 200,004
    int*            cursor    = (int*)(ws + 26536580);           // 200,000
    int*            csr_src   = (int*)(ws + 26736580);           // 6,400,000
    int*            tmp       = (int*)(ws + 26736580);           // 200,000 overlay (dead before k_fill)
    int*            blocksum  = (int*)(ws + 33136580);           // 1,024
    int*            mask      = (int*)(ws + 33137604);           // 200,000
    int*            ctx_list  = (int*)(ws + 33337604);           // 24,576
    int*            ctx_count = (int*)(ws + 33362180);           // 4     (total ~33.4 MB)

    // cvtW also zeroes degi + mask + ctx_count (runs first)
    k_cvtW<<<N_PAD / 32, 256, 0, stream>>>(fcW, Wt, degi, mask, ctx_count);

    // CSR build
    k_count_degi<<<CE_BLKS, 256, 0, stream>>>(dst, degi);
    k_scan_block<<<196, 256, 0, stream>>>(degi, dis, tmp, blocksum);
    // fused: scan finish + ctx-list build (blocks 0..195)  ∥  layer-1 transform
    k_scanfin_tf<<<196 + 6250, 256, 0, stream>>>(tmp, blocksum, row_start, cursor,
                                                 ctx_idx, mask, ctx_list, ctx_count,
                                                 service_emb, W1, dis, h1);
    k_fill<<<CE_BLKS, 256, 0, stream>>>(src, dst, cursor, csr_src);

    // fused layer-1 agg + ReLU + layer-2 transform (g1 never leaves LDS)
    k_agg_tf<<<3125, 256, 0, stream>>>(row_start, csr_src, dis,
                                       (const unsigned int*)h1, b1, W2, h2b);
    // layer-2 agg over compact ctx list
    k_agg_ctx<<<N_CTX / 16, 256, 0, stream>>>(row_start, csr_src, dis,
                                              (const unsigned int*)h2b, b2,
                                              ctx_list, ctx_count, g);

    k_gather<<<BATCH * FIN / 256, 256, 0, stream>>>(user_idx, ctx_idx, user_emb, g, xb);

    k_gemm3<<<GEMM_BLKS, 256, 0, stream>>>((const short*)xb, Wt, fcb, out);
}